// Round 1
// baseline (96.408 us; speedup 1.0000x reference)
//
#include <hip/hip_runtime.h>
#include <hip/hip_bf16.h>

#define B_SZ 256
#define L_SZ 50
#define N_SZ 100000
#define D_SZ 128
#define NT ((N_SZ + 63) / 64)   // 1563 col-tiles of 64

typedef __attribute__((ext_vector_type(8))) short bf16x8;
typedef __attribute__((ext_vector_type(4))) float f32x4;

__device__ inline unsigned short f2bf(float f) {
    union { float f; unsigned u; } v; v.f = f;
    unsigned r = v.u + 0x7FFFu + ((v.u >> 16) & 1u);   // round-to-nearest-even
    return (unsigned short)(r >> 16);
}

// ---------------- kernel 1: qW1[d] = sum_e q[e] W1[e,d]; qW2; qsum; zero loss slot
__global__ __launch_bounds__(128) void k_prep(const float* __restrict__ W1,
                                              const float* __restrict__ W2,
                                              const float* __restrict__ q,
                                              float* __restrict__ wsf,
                                              float* __restrict__ loss_slot) {
    int d = threadIdx.x;
    float a1 = 0.f, a2 = 0.f;
    #pragma unroll 4
    for (int e = 0; e < D_SZ; ++e) {
        float qe = q[e];
        a1 += qe * W1[e * D_SZ + d];
        a2 += qe * W2[e * D_SZ + d];
    }
    wsf[d] = a1;
    wsf[D_SZ + d] = a2;
    __shared__ float red[D_SZ];
    red[d] = q[d];
    __syncthreads();
    if (d == 0) {
        float s = 0.f;
        for (int i = 0; i < D_SZ; ++i) s += red[i];
        wsf[2 * D_SZ] = s;      // qsum
        loss_slot[0] = 0.f;     // zero loss accumulator every launch
    }
}

// ---------------- kernel 2: per-b, gather v, compute att, u -> bf16
__global__ __launch_bounds__(128) void k_ub(const int* __restrict__ seeds,
                                            const float* __restrict__ E,
                                            const float* __restrict__ pe,
                                            const float* __restrict__ wsf,
                                            const float* __restrict__ b_att,
                                            unsigned short* __restrict__ u_bf) {
    __shared__ float vbuf[L_SZ][D_SZ + 1];   // +1 pad: bank-conflict-free row sweeps
    __shared__ float att[L_SZ];
    __shared__ float c2s;
    __shared__ float qw1s[D_SZ], qw2s[D_SZ];
    int b = blockIdx.x, d = threadIdx.x;
    qw1s[d] = wsf[d];
    qw2s[d] = wsf[D_SZ + d];

    for (int l = 0; l < L_SZ; ++l) {
        int s = seeds[b * L_SZ + l];
        vbuf[l][d] = E[(size_t)s * D_SZ + d] + pe[l * D_SZ + d];
    }
    __syncthreads();

    if (d < L_SZ) {                 // att_raw[l] = v[l,:] . qW1
        float acc = 0.f;
        #pragma unroll 4
        for (int k = 0; k < D_SZ; ++k) acc += vbuf[d][k] * qw1s[k];
        att[d] = acc;
    } else if (d == L_SZ) {         // c2 = vn . qW2
        float acc = 0.f;
        #pragma unroll 4
        for (int k = 0; k < D_SZ; ++k) acc += vbuf[L_SZ - 1][k] * qw2s[k];
        c2s = acc;
    }
    __syncthreads();

    float add = c2s + b_att[0] * wsf[2 * D_SZ];
    float u = 0.f;
    #pragma unroll 5
    for (int l = 0; l < L_SZ; ++l) u += (att[l] + add) * vbuf[l][d];
    u_bf[b * D_SZ + d] = f2bf(u);
}

// ---------------- kernel 3: scores = u @ E^T + bias (bf16 MFMA), partial sum-exp
__global__ __launch_bounds__(256) void k_gemm(const float* __restrict__ E,
                                              const float* __restrict__ out_bias,
                                              const unsigned short* __restrict__ u_bf,
                                              float* __restrict__ scores,
                                              float* __restrict__ partial) {
    __shared__ float lds_sum[B_SZ];
    int tid = threadIdx.x;
    int w = tid >> 6, lane = tid & 63;
    lds_sum[tid] = 0.f;
    __syncthreads();

    int nc = blockIdx.x * 64 + w * 16;       // this wave's 16-col panel
    int col = lane & 15;
    int n = nc + col;
    int nclamp = n < N_SZ ? n : N_SZ - 1;
    bool valid = (n < N_SZ);
    int kb = (lane >> 4) * 8;                // k sub-chunk within K=32

    // B fragments: E rows (= score cols), cast f32->bf16
    bf16x8 bfrag[4];
    #pragma unroll
    for (int ks = 0; ks < 4; ++ks) {
        const float* p = E + (size_t)nclamp * D_SZ + ks * 32 + kb;
        float4 x = *(const float4*)p;
        float4 y = *(const float4*)(p + 4);
        bf16x8 f;
        f[0] = (short)f2bf(x.x); f[1] = (short)f2bf(x.y);
        f[2] = (short)f2bf(x.z); f[3] = (short)f2bf(x.w);
        f[4] = (short)f2bf(y.x); f[5] = (short)f2bf(y.y);
        f[6] = (short)f2bf(y.z); f[7] = (short)f2bf(y.w);
        bfrag[ks] = f;
    }
    float bias = out_bias[nclamp];

    for (int rs = 0; rs < 16; ++rs) {        // 16 row-subtiles cover all 256 b-rows
        f32x4 acc = {0.f, 0.f, 0.f, 0.f};
        int r = rs * 16 + col;               // A-frag row = lane&15
        const unsigned short* up = u_bf + r * D_SZ + kb;
        #pragma unroll
        for (int ks = 0; ks < 4; ++ks) {
            bf16x8 a = *(const bf16x8*)(up + ks * 32);
            acc = __builtin_amdgcn_mfma_f32_16x16x32_bf16(a, bfrag[ks], acc, 0, 0, 0);
        }
        // C layout: col = lane&15, row = (lane>>4)*4 + g  [m89-verified]
        int row0 = rs * 16 + (lane >> 4) * 4;
        #pragma unroll
        for (int g = 0; g < 4; ++g) {
            float c = acc[g] + bias;
            int row = row0 + g;
            if (valid) scores[(size_t)row * N_SZ + n] = c;
            float p = valid ? __expf(c) : 0.f;
            p += __shfl_xor(p, 1, 16);
            p += __shfl_xor(p, 2, 16);
            p += __shfl_xor(p, 4, 16);
            p += __shfl_xor(p, 8, 16);
            if (col == 0) atomicAdd(&lds_sum[row], p);
        }
    }
    __syncthreads();
    partial[(size_t)blockIdx.x * B_SZ + tid] = lds_sum[tid];
}

// ---------------- kernel 4: per-row logsumexp + NLL mean
__global__ __launch_bounds__(256) void k_loss(const float* __restrict__ partial,
                                              const float* __restrict__ scores,
                                              const int* __restrict__ labels,
                                              float* __restrict__ out_loss) {
    int b = blockIdx.x, t = threadIdx.x;
    float acc = 0.f;
    for (int i = t; i < NT; i += 256) acc += partial[(size_t)i * B_SZ + b];
    __shared__ float red[256];
    red[t] = acc;
    __syncthreads();
    for (int s = 128; s > 0; s >>= 1) {
        if (t < s) red[t] += red[t + s];
        __syncthreads();
    }
    if (t == 0) {
        int lab = labels[b];
        float val = scores[(size_t)b * N_SZ + lab] - logf(red[0]);
        atomicAdd(out_loss, -val * (1.0f / (float)B_SZ));
    }
}

extern "C" void kernel_launch(void* const* d_in, const int* in_sizes, int n_in,
                              void* d_out, int out_size, void* d_ws, size_t ws_size,
                              hipStream_t stream) {
    const int*   seeds    = (const int*)d_in[0];
    const int*   labels   = (const int*)d_in[1];
    const float* E        = (const float*)d_in[2];
    const float* W1       = (const float*)d_in[3];
    const float* W2       = (const float*)d_in[4];
    const float* q        = (const float*)d_in[5];
    const float* b_att    = (const float*)d_in[6];
    const float* out_bias = (const float*)d_in[7];
    const float* pe       = (const float*)d_in[8];

    float* scores = (float*)d_out;
    float* loss   = scores + (size_t)B_SZ * N_SZ;

    // ws layout: [0,512) qW1 | [512,1024) qW2 | [1024] qsum | @2048 u_bf16 (64KB) | @67584 partial (1.6MB)
    float*          wsf     = (float*)d_ws;
    unsigned short* u_bf    = (unsigned short*)((char*)d_ws + 2048);
    float*          partial = (float*)((char*)d_ws + 67584);

    k_prep<<<1, 128, 0, stream>>>(W1, W2, q, wsf, loss);
    k_ub<<<B_SZ, 128, 0, stream>>>(seeds, E, pe, wsf, b_att, u_bf);
    k_gemm<<<NT, 256, 0, stream>>>(E, out_bias, u_bf, scores, partial);
    k_loss<<<B_SZ, 256, 0, stream>>>(partial, scores, labels, loss);
}